// Round 1
// baseline (569.160 us; speedup 1.0000x reference)
//
#include <hip/hip_runtime.h>

#define QN    313
#define KTOP  5
#define HWPX  9216          // 96*96
#define BATCH 32
#define MPIX  (BATCH * HWPX) // 294912, divisible by 256
#define FLT_BIG 3.402823466e+38f

__global__ __launch_bounds__(256) void mce_main(
    const float* __restrict__ logits,   // (B, Q, H, W)
    const float* __restrict__ tab,      // (B, 2, H, W)
    const float* __restrict__ centers,  // (Q, 2)
    const float* __restrict__ cw,       // (Q,)
    float* __restrict__ out)            // scalar accumulator
{
    __shared__ float2 s_c[QN];
    __shared__ float  s_w[QN];
    for (int i = threadIdx.x; i < QN; i += 256) {
        s_c[i] = make_float2(centers[2 * i], centers[2 * i + 1]);
        s_w[i] = cw[i];
    }
    __syncthreads();

    const int m  = blockIdx.x * 256 + threadIdx.x;
    const int b  = m / HWPX;
    const int hw = m - b * HWPX;

    const float pa = tab[(size_t)(b * 2) * HWPX + hw] * 128.f;
    const float pb = tab[(size_t)(b * 2 + 1) * HWPX + hw] * 128.f;

    // ---- Phase 1: top-5 smallest squared distances (branchless sorted insert)
    float e0 = FLT_BIG, e1 = FLT_BIG, e2 = FLT_BIG, e3 = FLT_BIG, e4 = FLT_BIG;
    int   j0 = 0, j1 = 0, j2 = 0, j3 = 0, j4 = 0;
    for (int q = 0; q < QN; ++q) {
        float2 c = s_c[q];
        float da = pa - c.x;
        float db = pb - c.y;
        float dist = fmaf(da, da, db * db);
        bool c0 = dist < e0, c1 = dist < e1, c2 = dist < e2,
             c3 = dist < e3, c4 = dist < e4;
        e4 = c3 ? e3 : (c4 ? dist : e4);  j4 = c3 ? j3 : (c4 ? q : j4);
        e3 = c2 ? e2 : (c3 ? dist : e3);  j3 = c2 ? j2 : (c3 ? q : j3);
        e2 = c1 ? e1 : (c2 ? dist : e2);  j2 = c1 ? j1 : (c2 ? q : j2);
        e1 = c0 ? e0 : (c1 ? dist : e1);  j1 = c0 ? j0 : (c1 ? q : j1);
        e0 = c0 ? dist : e0;              j0 = c0 ? q : j0;
    }

    // soft-encode weights: exp(-d2 / (2*sigma^2)) = exp(-d2/50)
    float w0 = __expf(e0 * -0.02f);
    float w1 = __expf(e1 * -0.02f);
    float w2 = __expf(e2 * -0.02f);
    float w3 = __expf(e3 * -0.02f);
    float w4 = __expf(e4 * -0.02f);
    float wsum = w0 + w1 + w2 + w3 + w4;
    float inv  = 1.f / (wsum + 1e-8f);
    w0 *= inv; w1 *= inv; w2 *= inv; w3 *= inv; w4 *= inv;
    float wnorm = wsum * inv;             // sum of normalized weights
    float pw = s_w[j0];                   // class weight of nearest bin

    // ---- Phase 2: online log-softmax over Q + capture top-5 logits
    const float* lp = logits + (size_t)b * QN * HWPX + hw;
    float mx = -FLT_BIG;
    float ssum = 0.f;
    float dot = 0.f;
    #pragma unroll 4
    for (int q = 0; q < QN; ++q) {
        float x = lp[(size_t)q * HWPX];
        float wq = 0.f;
        wq = (q == j0) ? w0 : wq;
        wq = (q == j1) ? w1 : wq;
        wq = (q == j2) ? w2 : wq;
        wq = (q == j3) ? w3 : wq;
        wq = (q == j4) ? w4 : wq;
        dot = fmaf(wq, x, dot);
        float d = x - mx;
        float e = __expf(-fabsf(d));
        bool gt = d > 0.f;
        ssum = gt ? fmaf(ssum, e, 1.f) : (ssum + e);
        mx   = gt ? x : mx;
    }

    float ce = (mx + __logf(ssum)) * wnorm - dot;
    float contrib = ce * pw * (1.0f / (float)MPIX);

    // ---- Reduce: wave shuffle -> LDS -> one atomic per block
    #pragma unroll
    for (int off = 32; off >= 1; off >>= 1)
        contrib += __shfl_down(contrib, off, 64);

    __shared__ float s_red[4];
    int lane = threadIdx.x & 63;
    int wid  = threadIdx.x >> 6;
    if (lane == 0) s_red[wid] = contrib;
    __syncthreads();
    if (threadIdx.x == 0)
        atomicAdd(out, s_red[0] + s_red[1] + s_red[2] + s_red[3]);
}

extern "C" void kernel_launch(void* const* d_in, const int* in_sizes, int n_in,
                              void* d_out, int out_size, void* d_ws, size_t ws_size,
                              hipStream_t stream) {
    const float* logits  = (const float*)d_in[0];
    const float* tab     = (const float*)d_in[1];
    const float* centers = (const float*)d_in[2];
    const float* cwt     = (const float*)d_in[3];
    float* out = (float*)d_out;

    hipMemsetAsync(out, 0, sizeof(float), stream);
    mce_main<<<MPIX / 256, 256, 0, stream>>>(logits, tab, centers, cwt, out);
}

// Round 2
// 513.639 us; speedup vs baseline: 1.1081x; 1.1081x over previous
//
#include <hip/hip_runtime.h>

#define QN    313
#define HWPX  9216           // 96*96
#define BATCH 32
#define MPIX  (BATCH * HWPX) // 294912
#define BLKPB 36             // blocks per batch image: 9216/256
#define FLT_BIG 3.402823466e+38f

__global__ __launch_bounds__(256) void mce_main(
    const float* __restrict__ logits,   // (B, Q, H, W)
    const float* __restrict__ tab,      // (B, 2, H, W)
    const float* __restrict__ centers,  // (Q, 2)
    const float* __restrict__ cw,       // (Q,)
    float* __restrict__ out)
{
    __shared__ float2 s_c[QN];
    __shared__ float  s_w[QN];
    for (int i = threadIdx.x; i < QN; i += 256) {
        s_c[i] = make_float2(centers[2 * i], centers[2 * i + 1]);
        s_w[i] = cw[i];
    }
    __syncthreads();

    // block-uniform batch index & hw base -> scalar-friendly addressing
    const int bb     = blockIdx.x / BLKPB;
    const int hwBase = (blockIdx.x - bb * BLKPB) * 256;
    const int hw     = hwBase + threadIdx.x;

    const float* tabB = tab + (size_t)bb * 2 * HWPX;
    const float pa = tabB[hw] * 128.f;
    const float pb = tabB[HWPX + hw] * 128.f;

    // ---- Phase 1: top-5 via packed (dist|index) min/max insertion network
    unsigned e0 = 0xFFFFFFFFu, e1 = 0xFFFFFFFFu, e2 = 0xFFFFFFFFu,
             e3 = 0xFFFFFFFFu, e4 = 0xFFFFFFFFu;
    for (int q = 0; q < QN; ++q) {
        float2 c = s_c[q];
        float da = pa - c.x;
        float db = pb - c.y;
        float dist = fmaf(da, da, db * db);
        unsigned v = (__float_as_uint(dist) & 0xFFFFFE00u) | (unsigned)q;
        unsigned t;
        t = min(e0, v); v = max(e0, v); e0 = t;
        t = min(e1, v); v = max(e1, v); e1 = t;
        t = min(e2, v); v = max(e2, v); e2 = t;
        t = min(e3, v); v = max(e3, v); e3 = t;
        e4 = min(e4, v);
    }

    const unsigned j0 = e0 & 0x1FFu, j1 = e1 & 0x1FFu, j2 = e2 & 0x1FFu,
                   j3 = e3 & 0x1FFu, j4 = e4 & 0x1FFu;
    float w0 = __expf(__uint_as_float(e0 & 0xFFFFFE00u) * -0.02f);
    float w1 = __expf(__uint_as_float(e1 & 0xFFFFFE00u) * -0.02f);
    float w2 = __expf(__uint_as_float(e2 & 0xFFFFFE00u) * -0.02f);
    float w3 = __expf(__uint_as_float(e3 & 0xFFFFFE00u) * -0.02f);
    float w4 = __expf(__uint_as_float(e4 & 0xFFFFFE00u) * -0.02f);
    float wsum = w0 + w1 + w2 + w3 + w4;
    float inv  = 1.f / (wsum + 1e-8f);
    w0 *= inv; w1 *= inv; w2 *= inv; w3 *= inv; w4 *= inv;
    const float wnorm = wsum * inv;
    const float pw = s_w[j0];

    // ---- Phase 2: streaming log-softmax, 4 independent online states
    const float* lpB = logits + (size_t)bb * QN * HWPX;
    float mxs[4] = {-FLT_BIG, -FLT_BIG, -FLT_BIG, -FLT_BIG};
    float sss[4] = {0.f, 0.f, 0.f, 0.f};
    float dot = 0.f;

    int q = 0;
    #pragma unroll 2
    for (; q <= QN - 4; q += 4) {
        #pragma unroll
        for (int u = 0; u < 4; ++u) {
            const unsigned qq = (unsigned)(q + u);
            const float x = lpB[qq * HWPX + hw];
            float wq = 0.f;
            wq = (qq == j0) ? w0 : wq;
            wq = (qq == j1) ? w1 : wq;
            wq = (qq == j2) ? w2 : wq;
            wq = (qq == j3) ? w3 : wq;
            wq = (qq == j4) ? w4 : wq;
            dot = fmaf(wq, x, dot);
            const float d  = x - mxs[u];
            const float e  = __expf(-fabsf(d));
            const bool  gt = d > 0.f;
            const float sa = fmaf(sss[u], e, 1.f);
            const float sb = sss[u] + e;
            sss[u] = gt ? sa : sb;
            mxs[u] = gt ? x : mxs[u];
        }
    }
    for (; q < QN; ++q) {   // remainder (313 = 4*78 + 1)
        const unsigned qq = (unsigned)q;
        const float x = lpB[qq * HWPX + hw];
        float wq = 0.f;
        wq = (qq == j0) ? w0 : wq;
        wq = (qq == j1) ? w1 : wq;
        wq = (qq == j2) ? w2 : wq;
        wq = (qq == j3) ? w3 : wq;
        wq = (qq == j4) ? w4 : wq;
        dot = fmaf(wq, x, dot);
        const float d  = x - mxs[0];
        const float e  = __expf(-fabsf(d));
        const bool  gt = d > 0.f;
        const float sa = fmaf(sss[0], e, 1.f);
        const float sb = sss[0] + e;
        sss[0] = gt ? sa : sb;
        mxs[0] = gt ? x : mxs[0];
    }

    // merge the 4 online-softmax states
    float M = mxs[0], S = sss[0];
    #pragma unroll
    for (int u = 1; u < 4; ++u) {
        const float Mn = fmaxf(M, mxs[u]);
        S = fmaf(S, __expf(M - Mn), sss[u] * __expf(mxs[u] - Mn));
        M = Mn;
    }

    const float ce = (M + __logf(S)) * wnorm - dot;
    float contrib = ce * pw * (1.0f / (float)MPIX);

    // ---- Reduce: wave shuffle -> LDS -> one atomic per block
    #pragma unroll
    for (int off = 32; off >= 1; off >>= 1)
        contrib += __shfl_down(contrib, off, 64);

    __shared__ float s_red[4];
    const int lane = threadIdx.x & 63;
    const int wid  = threadIdx.x >> 6;
    if (lane == 0) s_red[wid] = contrib;
    __syncthreads();
    if (threadIdx.x == 0)
        atomicAdd(out, s_red[0] + s_red[1] + s_red[2] + s_red[3]);
}

extern "C" void kernel_launch(void* const* d_in, const int* in_sizes, int n_in,
                              void* d_out, int out_size, void* d_ws, size_t ws_size,
                              hipStream_t stream) {
    const float* logits  = (const float*)d_in[0];
    const float* tab     = (const float*)d_in[1];
    const float* centers = (const float*)d_in[2];
    const float* cwt     = (const float*)d_in[3];
    float* out = (float*)d_out;

    hipMemsetAsync(out, 0, sizeof(float), stream);
    mce_main<<<MPIX / 256, 256, 0, stream>>>(logits, tab, centers, cwt, out);
}